// Round 19
// baseline (427.967 us; speedup 1.0000x reference)
//
#include <hip/hip_runtime.h>
#include <hip/hip_bf16.h>

// SemWindowAttention: B=8, H=W=256, C=256, WS=8, NCLS=18
// windows = 8*32*32 = 8192, tokens/window = 64
//
// Algebraic fusion: softmax rows sum to 1 =>
//   out1 = gamma*( P @ (x @ Wf) + bf ) + x,  Wf = Wv@Wres, bf = bv@Wres + bres
//
// Base = R15/R18 champion (299us): two windows per block, lgkm-only barriers,
// chunk-granular store cadence (clean-HBM law). This round: TOKEN-SLICED
// U-sweep. Wave w computes U^T[all 64 ch of chunk][tokens w*16..+16): per
// k-step only 1 xs A-frag per window (vs 4), and the 4 wft B-frags are
// IDENTICAL across all waves+windows -> L1-broadcast (chunk slice = 32KB =
// L1). Tail LDS ops 76 -> 28 per wave/chunk. Utc bounce becomes cross-wave
// (2 BARs/chunk); PV + stores unchanged (wave owns 16-ch slice).

typedef __bf16 bf16_t;
typedef __bf16 bf16x8 __attribute__((ext_vector_type(8)));
typedef __bf16 bf16x4 __attribute__((ext_vector_type(4)));
typedef float  f32x4  __attribute__((ext_vector_type(4)));

#define MFMA16(a, b, c) __builtin_amdgcn_mfma_f32_16x16x32_bf16((a), (b), (c), 0, 0, 0)
// All inter-phase deps are through LDS; let global stores fly across barriers.
#define BAR() do { asm volatile("s_waitcnt lgkmcnt(0)" ::: "memory"); \
                   __builtin_amdgcn_s_barrier(); } while (0)

static constexpr int kC = 256, kNCLS = 18;
// ws bf16 layout (element offsets)
static constexpr int WQT_OFF = 0;        // WqT[32][256]  (n-major, zero-padded 18..31)
static constexpr int WKT_OFF = 8192;     // WkT[32][256]
static constexpr int WFT_OFF = 16384;    // WfT[256][256], WfT[n][k] = Wf[k][n]
static constexpr int BF_BYTE_OFF = 81920 * 2;  // float bf[256] after bf16 section

// XOR swizzle: byte ^= (row&7)<<4  <=>  elem ^= (row&7)<<3 (bf16). Bijective per
// row; fragment (16B) / x4 (8B) accesses keep alignment.
__device__ __forceinline__ int xs_i(int r, int c) { return (r << 8) + (c ^ ((r & 7) << 3)); }
__device__ __forceinline__ int sb_i(int r, int c) { return (r << 6) + (c ^ ((r & 7) << 3)); }

__global__ __launch_bounds__(256) void prep_kernel(
    const float* __restrict__ Wq, const float* __restrict__ Wk,
    const float* __restrict__ Wv, const float* __restrict__ bv,
    const float* __restrict__ Wres, const float* __restrict__ bres,
    bf16_t* __restrict__ wsb, float* __restrict__ bff)
{
  const int blk = blockIdx.x, t = threadIdx.x;
  if (blk < 256) {
    // WfT[n][k] = sum_j Wv[k][j] * Wres[j][n], one block per n, thread = k
    __shared__ float wcol[256];
    const int n = blk;
    wcol[t] = Wres[t * kC + n];
    __syncthreads();
    float acc = 0.f;
    const float* wvrow = Wv + (size_t)t * kC;
#pragma unroll 4
    for (int j = 0; j < 256; j += 4) {
      f32x4 a = *(const f32x4*)(wvrow + j);
      acc += a[0] * wcol[j] + a[1] * wcol[j + 1] + a[2] * wcol[j + 2] + a[3] * wcol[j + 3];
    }
    wsb[WFT_OFF + n * kC + t] = (bf16_t)acc;
  } else if (blk == 256) {
    // bf[n] = sum_j bv[j]*Wres[j][n] + bres[n]
    float acc = bres[t];
    for (int j = 0; j < 256; ++j) acc += bv[j] * Wres[j * kC + t];
    bff[t] = acc;
  } else {
    int tid = (blk - 257) * 256 + t;  // 0..16383
    if (tid < 8192) {
      int n = tid >> 8, k = tid & 255;
      wsb[WQT_OFF + tid] = (n < kNCLS) ? (bf16_t)Wq[k * kNCLS + n] : (bf16_t)0.0f;
    } else {
      int u = tid - 8192;
      int n = u >> 8, k = u & 255;
      wsb[WKT_OFF + u] = (n < kNCLS) ? (bf16_t)Wk[k * kNCLS + n] : (bf16_t)0.0f;
    }
  }
}

__global__ __launch_bounds__(256, 2) void semwin_main(
    const float* __restrict__ x,
    const float* __restrict__ bq, const float* __restrict__ bk,
    const float* __restrict__ gamma,
    const bf16_t* __restrict__ wsb, const float* __restrict__ bff,
    float* __restrict__ out0, float* __restrict__ out1)
{
  // LDS: 2*32768 + 2*8192 = 81920 B -> 2 blocks/CU (163840/2)
  __shared__ bf16_t xsf0[64 * 256];
  __shared__ bf16_t xsf1[64 * 256];
  __shared__ bf16_t sbf0[64 * 64];
  __shared__ bf16_t sbf1[64 * 64];

  const int tid  = threadIdx.x;
  const int wave = tid >> 6;
  const int lane = tid & 63;
  const int l15  = lane & 15;
  const int g    = lane >> 4;

  // two adjacent windows: wid2 even -> same b, wh; ww and ww+1
  const int wid2 = blockIdx.x << 1;
  const int b    = wid2 >> 10;
  const int wh   = (wid2 >> 5) & 31;
  const int ww   = wid2 & 31;
  const int pix0 = (b << 16) + (wh << 11) + (ww << 3);
  const int pix1 = pix0 + 8;
  // pixel(t) = pixbase + (t>>3)*256 + (t&7)

  const f32x4 fzero = {0.f, 0.f, 0.f, 0.f};
  const float gm = gamma[0];

  // ---- stage both x windows (issue ALL loads, then cvt+write) ----
  {
    const int t = tid >> 2;
    const int q = tid & 3;
    const int ro = ((t >> 3) << 8) + (t & 7);
    const float* s0 = x + (size_t)(pix0 + ro) * kC + q * 8;
    const float* s1 = s0 + 8 * kC;  // pix1 = pix0 + 8 pixels
    f32x4 la[8][2], lb[8][2];       // 128 VGPRs, dead after this phase
#pragma unroll
    for (int i = 0; i < 8; ++i) {
      la[i][0] = *(const f32x4*)(s0 + i * 32);
      la[i][1] = *(const f32x4*)(s0 + i * 32 + 4);
      lb[i][0] = *(const f32x4*)(s1 + i * 32);
      lb[i][1] = *(const f32x4*)(s1 + i * 32 + 4);
    }
#pragma unroll
    for (int i = 0; i < 8; ++i) {
      bf16x8 v0, v1;
#pragma unroll
      for (int r = 0; r < 4; ++r) {
        v0[r] = (bf16_t)la[i][0][r]; v0[4 + r] = (bf16_t)la[i][1][r];
        v1[r] = (bf16_t)lb[i][0][r]; v1[4 + r] = (bf16_t)lb[i][1][r];
      }
      *(bf16x8*)&xsf0[xs_i(t, i * 32 + q * 8)] = v0;
      *(bf16x8*)&xsf1[xs_i(t, i * 32 + q * 8)] = v1;
    }
  }
  BAR();

  // ---- phase A: Q proj (waves 0,1) / K proj (waves 2,3), both windows ----
  // sbf rows = tokens, cols 0..31 = Q (padded), cols 32..63 = K.
  {
    const bf16_t* wt   = wsb + ((wave < 2) ? WQT_OFF : WKT_OFF);
    const float*  bias = (wave < 2) ? bq : bk;
    const int mbase = (wave & 1) << 5;  // rows 0..31 or 32..63
    const int cofs  = (wave < 2) ? 0 : 32;
    const bool isQ  = (wave < 2);
    f32x4 acc[2][2][2];  // [win][mt][nt]
#pragma unroll
    for (int w2 = 0; w2 < 2; ++w2)
#pragma unroll
      for (int mt = 0; mt < 2; ++mt)
#pragma unroll
        for (int nt = 0; nt < 2; ++nt) acc[w2][mt][nt] = fzero;
#pragma unroll
    for (int k0 = 0; k0 < 256; k0 += 32) {
      bf16x8 b0 = *(const bf16x8*)(wt + l15 * 256 + k0 + g * 8);
      bf16x8 b1 = *(const bf16x8*)(wt + (16 + l15) * 256 + k0 + g * 8);
#pragma unroll
      for (int w2 = 0; w2 < 2; ++w2) {
        const bf16_t* xs = w2 ? xsf1 : xsf0;
        bf16x8 a0 = *(const bf16x8*)&xs[xs_i(mbase + l15, k0 + g * 8)];
        bf16x8 a1 = *(const bf16x8*)&xs[xs_i(mbase + 16 + l15, k0 + g * 8)];
        acc[w2][0][0] = MFMA16(a0, b0, acc[w2][0][0]);
        acc[w2][0][1] = MFMA16(a0, b1, acc[w2][0][1]);
        acc[w2][1][0] = MFMA16(a1, b0, acc[w2][1][0]);
        acc[w2][1][1] = MFMA16(a1, b1, acc[w2][1][1]);
      }
    }
#pragma unroll
    for (int w2 = 0; w2 < 2; ++w2) {
      bf16_t* sb = w2 ? sbf1 : sbf0;
      const int pix = w2 ? pix1 : pix0;
#pragma unroll
      for (int nt = 0; nt < 2; ++nt) {
        const int coln = (nt << 4) + l15;
        const float bval = (coln < kNCLS) ? bias[coln] : 0.f;
#pragma unroll
        for (int mt = 0; mt < 2; ++mt) {
#pragma unroll
          for (int r = 0; r < 4; ++r) {
            const int row = mbase + (mt << 4) + (g << 2) + r;  // token
            const float v = acc[w2][mt][nt][r] + bval;
            sb[sb_i(row, cofs + coln)] = (bf16_t)v;
            if (isQ && coln < kNCLS) {
              out0[(size_t)(pix + ((row >> 3) << 8) + (row & 7)) * kNCLS + coln] = v;
            }
          }
        }
      }
    }
  }
  BAR();

  // ---- phase S: S = Q K^T + in-register softmax -> Ps, both windows ----
  {
    const int mbase = wave << 4;
    f32x4 s[2][4];
#pragma unroll
    for (int w2 = 0; w2 < 2; ++w2) {
      const bf16_t* sb = w2 ? sbf1 : sbf0;
      const bf16x8 aq = *(const bf16x8*)&sb[sb_i(mbase + l15, g * 8)];
#pragma unroll
      for (int nt = 0; nt < 4; ++nt) {
        bf16x8 bk8 = *(const bf16x8*)&sb[sb_i((nt << 4) + l15, 32 + g * 8)];
        s[w2][nt] = MFMA16(aq, bk8, fzero);
      }
    }
    BAR();  // all waves done reading Q/K (Ps aliases them)
#pragma unroll
    for (int w2 = 0; w2 < 2; ++w2) {
      bf16_t* sb = w2 ? sbf1 : sbf0;
#pragma unroll
      for (int r = 0; r < 4; ++r) {
        float m = fmaxf(fmaxf(s[w2][0][r], s[w2][1][r]), fmaxf(s[w2][2][r], s[w2][3][r]));
#pragma unroll
        for (int off = 1; off < 16; off <<= 1) m = fmaxf(m, __shfl_xor(m, off));
        float e0 = __expf(s[w2][0][r] - m), e1 = __expf(s[w2][1][r] - m);
        float e2 = __expf(s[w2][2][r] - m), e3 = __expf(s[w2][3][r] - m);
        float sum = (e0 + e1) + (e2 + e3);
#pragma unroll
        for (int off = 1; off < 16; off <<= 1) sum += __shfl_xor(sum, off);
        const float inv = 1.0f / sum;
        const int row = mbase + (g << 2) + r;
        sb[sb_i(row, l15)]      = (bf16_t)(e0 * inv);
        sb[sb_i(row, 16 + l15)] = (bf16_t)(e1 * inv);
        sb[sb_i(row, 32 + l15)] = (bf16_t)(e2 * inv);
        sb[sb_i(row, 48 + l15)] = (bf16_t)(e3 * inv);
      }
    }
  }
  BAR();  // P visible to all waves

  // ---- hoist P fragments to registers, both windows (64 VGPRs) ----
  bf16x8 bp[2][4][2];
#pragma unroll
  for (int w2 = 0; w2 < 2; ++w2) {
    const bf16_t* sb = w2 ? sbf1 : sbf0;
#pragma unroll
    for (int nt = 0; nt < 4; ++nt) {
      bp[w2][nt][0] = *(const bf16x8*)&sb[sb_i((nt << 4) + l15, g * 8)];
      bp[w2][nt][1] = *(const bf16x8*)&sb[sb_i((nt << 4) + l15, 32 + g * 8)];
    }
  }
  // NOTE: no BAR yet -- Bc0's k-loop touches no LDS writes; the BAR before the
  // first Utc write protects Ps for all waves' hoists AND lets hoist latency
  // hide under Bc0's compute.

  // ---- token-sliced U-sweep: wave w computes U^T[all 64 ch][tokens w*16..+16)
  // Per k0: 4 wft B-frags (IDENTICAL across waves+windows -> L1 broadcast) +
  // 1 xs A-frag per window. accV[w2][ct][r] =
  //   U^T[ch = chunk*64 + ct*16 + l15][token = wave*16 + g*4 + r]
  auto bc_kloop = [&](int chunk, f32x4 (&accV)[2][4]) {
    const bf16_t* wftc = wsb + WFT_OFF + (size_t)((chunk << 6) + l15) * 256;
#pragma unroll
    for (int w2 = 0; w2 < 2; ++w2)
#pragma unroll
      for (int ct = 0; ct < 4; ++ct) accV[w2][ct] = fzero;
#pragma unroll
    for (int k0 = 0; k0 < 256; k0 += 32) {
      bf16x8 bfr[4];
#pragma unroll
      for (int ct = 0; ct < 4; ++ct)
        bfr[ct] = *(const bf16x8*)(wftc + ct * 16 * 256 + k0 + g * 8);
#pragma unroll
      for (int w2 = 0; w2 < 2; ++w2) {
        const bf16_t* xs = w2 ? xsf1 : xsf0;
        bf16x8 af = *(const bf16x8*)&xs[xs_i((wave << 4) + l15, k0 + g * 8)];
        accV[w2][0] = MFMA16(af, bfr[0], accV[w2][0]);
        accV[w2][1] = MFMA16(af, bfr[1], accV[w2][1]);
        accV[w2][2] = MFMA16(af, bfr[2], accV[w2][2]);
        accV[w2][3] = MFMA16(af, bfr[3], accV[w2][3]);
      }
    }
  };

  f32x4 accV[2][4];  // [win][ct]
  bc_kloop(0, accV);
  BAR();  // Ps-protect (hoists done everywhere) + cadence anchor

  for (int chunk = 0; chunk < 4; ++chunk) {
    // ---- cross-wave Utc write: wave w fills token-cols [w*16,+16) of every
    // ch row; rows ct*16+l15 over 4 ct tiles cover all 64 rows. ----
#pragma unroll
    for (int w2 = 0; w2 < 2; ++w2) {
      bf16_t* sb = w2 ? sbf1 : sbf0;
#pragma unroll
      for (int ct = 0; ct < 4; ++ct) {
        bf16x4 pk;
#pragma unroll
        for (int r = 0; r < 4; ++r) pk[r] = (bf16_t)accV[w2][ct][r];
        *(bf16x4*)&sb[sb_i((ct << 4) + l15, (wave << 4) + (g << 2))] = pk;
      }
    }
    BAR();  // Utc complete across waves

    // ---- PV + fused epilogue (wave owns ch slice [wave*16,+16)) ----
    const int c2 = (chunk << 6) + (wave << 4) + (g << 2);
    const f32x4 bfv = *(const f32x4*)(bff + c2);
#pragma unroll
    for (int w2 = 0; w2 < 2; ++w2) {
      const bf16_t* sb = w2 ? sbf1 : sbf0;
      const bf16_t* xs = w2 ? xsf1 : xsf0;
      const int pix = w2 ? pix1 : pix0;
      const bf16x8 av0 = *(const bf16x8*)&sb[sb_i((wave << 4) + l15, g * 8)];
      const bf16x8 av1 = *(const bf16x8*)&sb[sb_i((wave << 4) + l15, 32 + g * 8)];
#pragma unroll
      for (int nt = 0; nt < 4; ++nt) {
        f32x4 accC = MFMA16(av0, bp[w2][nt][0], fzero);
        accC = MFMA16(av1, bp[w2][nt][1], accC);
        const int t = (nt << 4) + l15;
        const bf16x4 xv = *(const bf16x4*)&xs[xs_i(t, c2)];
        f32x4 o;
#pragma unroll
        for (int r = 0; r < 4; ++r)
          o[r] = gm * (accC[r] + bfv[r]) + (float)xv[r];
        *(f32x4*)(out1 + (size_t)(pix + ((t >> 3) << 8) + (t & 7)) * kC + c2) = o;
      }
    }
    // overlap next chunk's compute with this chunk's store drain
    if (chunk < 3) {
      bc_kloop(chunk + 1, accV);
      BAR();  // protect this chunk's Utc reads before next writes + cadence
    }
  }
}

extern "C" void kernel_launch(void* const* d_in, const int* in_sizes, int n_in,
                              void* d_out, int out_size, void* d_ws, size_t ws_size,
                              hipStream_t stream)
{
  const float* x     = (const float*)d_in[0];
  const float* Wq    = (const float*)d_in[1];
  const float* bq    = (const float*)d_in[2];
  const float* Wk    = (const float*)d_in[3];
  const float* bk    = (const float*)d_in[4];
  const float* Wv    = (const float*)d_in[5];
  const float* bv    = (const float*)d_in[6];
  const float* Wres  = (const float*)d_in[7];
  const float* bres  = (const float*)d_in[8];
  const float* gamma = (const float*)d_in[9];
  bf16_t* wsb = (bf16_t*)d_ws;                         // 81920 bf16 = 163840 B
  float*  bff = (float*)((char*)d_ws + BF_BYTE_OFF);   // + 1024 B
  float* out0 = (float*)d_out;                         // (8,256,256,18)
  float* out1 = out0 + (size_t)8 * 256 * 256 * 18;     // (8,256,256,256)

  prep_kernel<<<dim3(321), dim3(256), 0, stream>>>(Wq, Wk, Wv, bv, Wres, bres, wsb, bff);
  semwin_main<<<dim3(4096), dim3(256), 0, stream>>>(x, bq, bk, gamma, wsb, bff, out0, out1);
}

// Round 20
// 298.357 us; speedup vs baseline: 1.4344x; 1.4344x over previous
//
#include <hip/hip_runtime.h>
#include <hip/hip_bf16.h>

// SemWindowAttention: B=8, H=W=256, C=256, WS=8, NCLS=18
// windows = 8*32*32 = 8192, tokens/window = 64
//
// Algebraic fusion: softmax rows sum to 1 =>
//   out1 = gamma*( P @ (x @ Wf) + bf ) + x,  Wf = Wv@Wres, bf = bv@Wres + bres
//
// FINAL CHAMPION (R15, 298.8us; reproduced R18 at 300.1us). Locked after the
// full lever sweep: occupancy (2/3/4 wg: flat), barrier count (cadence-
// critical but otherwise flat), 2-window/block per-wave ILP (-5%, kept),
// pipelined tail (-1%, kept), reg-cached tail (R16: VGPR cliff +13%),
// nontemporal stores (R17: +46% writes), wider tail ILP (R13: +3%),
// T14/T5 (R14: neutral), token-sliced sweep (R19: +43%). Structure:
// two windows per block, wft B-frags shared across windows, software-
// pipelined tail (Bc_{c+1} under Cc_c's store drain), lgkm-only barriers,
// chunk-granular store cadence (clean-HBM law: drifted stores leak
// +140..440MB; barriered stores are clean at 563W/267F).

typedef __bf16 bf16_t;
typedef __bf16 bf16x8 __attribute__((ext_vector_type(8)));
typedef __bf16 bf16x4 __attribute__((ext_vector_type(4)));
typedef float  f32x4  __attribute__((ext_vector_type(4)));

#define MFMA16(a, b, c) __builtin_amdgcn_mfma_f32_16x16x32_bf16((a), (b), (c), 0, 0, 0)
// All inter-phase deps are through LDS; let global stores fly across barriers.
#define BAR() do { asm volatile("s_waitcnt lgkmcnt(0)" ::: "memory"); \
                   __builtin_amdgcn_s_barrier(); } while (0)

static constexpr int kC = 256, kNCLS = 18;
// ws bf16 layout (element offsets)
static constexpr int WQT_OFF = 0;        // WqT[32][256]  (n-major, zero-padded 18..31)
static constexpr int WKT_OFF = 8192;     // WkT[32][256]
static constexpr int WFT_OFF = 16384;    // WfT[256][256], WfT[n][k] = Wf[k][n]
static constexpr int BF_BYTE_OFF = 81920 * 2;  // float bf[256] after bf16 section

// XOR swizzle: byte ^= (row&7)<<4  <=>  elem ^= (row&7)<<3 (bf16). Bijective per
// row; fragment (16B) / x4 (8B) accesses keep alignment.
__device__ __forceinline__ int xs_i(int r, int c) { return (r << 8) + (c ^ ((r & 7) << 3)); }
__device__ __forceinline__ int sb_i(int r, int c) { return (r << 6) + (c ^ ((r & 7) << 3)); }

__global__ __launch_bounds__(256) void prep_kernel(
    const float* __restrict__ Wq, const float* __restrict__ Wk,
    const float* __restrict__ Wv, const float* __restrict__ bv,
    const float* __restrict__ Wres, const float* __restrict__ bres,
    bf16_t* __restrict__ wsb, float* __restrict__ bff)
{
  const int blk = blockIdx.x, t = threadIdx.x;
  if (blk < 256) {
    // WfT[n][k] = sum_j Wv[k][j] * Wres[j][n], one block per n, thread = k
    __shared__ float wcol[256];
    const int n = blk;
    wcol[t] = Wres[t * kC + n];
    __syncthreads();
    float acc = 0.f;
    const float* wvrow = Wv + (size_t)t * kC;
#pragma unroll 4
    for (int j = 0; j < 256; j += 4) {
      f32x4 a = *(const f32x4*)(wvrow + j);
      acc += a[0] * wcol[j] + a[1] * wcol[j + 1] + a[2] * wcol[j + 2] + a[3] * wcol[j + 3];
    }
    wsb[WFT_OFF + n * kC + t] = (bf16_t)acc;
  } else if (blk == 256) {
    // bf[n] = sum_j bv[j]*Wres[j][n] + bres[n]
    float acc = bres[t];
    for (int j = 0; j < 256; ++j) acc += bv[j] * Wres[j * kC + t];
    bff[t] = acc;
  } else {
    int tid = (blk - 257) * 256 + t;  // 0..16383
    if (tid < 8192) {
      int n = tid >> 8, k = tid & 255;
      wsb[WQT_OFF + tid] = (n < kNCLS) ? (bf16_t)Wq[k * kNCLS + n] : (bf16_t)0.0f;
    } else {
      int u = tid - 8192;
      int n = u >> 8, k = u & 255;
      wsb[WKT_OFF + u] = (n < kNCLS) ? (bf16_t)Wk[k * kNCLS + n] : (bf16_t)0.0f;
    }
  }
}

__global__ __launch_bounds__(256, 2) void semwin_main(
    const float* __restrict__ x,
    const float* __restrict__ bq, const float* __restrict__ bk,
    const float* __restrict__ gamma,
    const bf16_t* __restrict__ wsb, const float* __restrict__ bff,
    float* __restrict__ out0, float* __restrict__ out1)
{
  // LDS: 2*32768 + 2*8192 = 81920 B -> 2 blocks/CU (163840/2)
  __shared__ bf16_t xsf0[64 * 256];
  __shared__ bf16_t xsf1[64 * 256];
  __shared__ bf16_t sbf0[64 * 64];
  __shared__ bf16_t sbf1[64 * 64];

  const int tid  = threadIdx.x;
  const int wave = tid >> 6;
  const int lane = tid & 63;
  const int l15  = lane & 15;
  const int g    = lane >> 4;

  // two adjacent windows: wid2 even -> same b, wh; ww and ww+1
  const int wid2 = blockIdx.x << 1;
  const int b    = wid2 >> 10;
  const int wh   = (wid2 >> 5) & 31;
  const int ww   = wid2 & 31;
  const int pix0 = (b << 16) + (wh << 11) + (ww << 3);
  const int pix1 = pix0 + 8;
  // pixel(t) = pixbase + (t>>3)*256 + (t&7)

  const f32x4 fzero = {0.f, 0.f, 0.f, 0.f};
  const float gm = gamma[0];

  // ---- stage both x windows (issue ALL loads, then cvt+write) ----
  {
    const int t = tid >> 2;
    const int q = tid & 3;
    const int ro = ((t >> 3) << 8) + (t & 7);
    const float* s0 = x + (size_t)(pix0 + ro) * kC + q * 8;
    const float* s1 = s0 + 8 * kC;  // pix1 = pix0 + 8 pixels
    f32x4 la[8][2], lb[8][2];       // 128 VGPRs, dead after this phase
#pragma unroll
    for (int i = 0; i < 8; ++i) {
      la[i][0] = *(const f32x4*)(s0 + i * 32);
      la[i][1] = *(const f32x4*)(s0 + i * 32 + 4);
      lb[i][0] = *(const f32x4*)(s1 + i * 32);
      lb[i][1] = *(const f32x4*)(s1 + i * 32 + 4);
    }
#pragma unroll
    for (int i = 0; i < 8; ++i) {
      bf16x8 v0, v1;
#pragma unroll
      for (int r = 0; r < 4; ++r) {
        v0[r] = (bf16_t)la[i][0][r]; v0[4 + r] = (bf16_t)la[i][1][r];
        v1[r] = (bf16_t)lb[i][0][r]; v1[4 + r] = (bf16_t)lb[i][1][r];
      }
      *(bf16x8*)&xsf0[xs_i(t, i * 32 + q * 8)] = v0;
      *(bf16x8*)&xsf1[xs_i(t, i * 32 + q * 8)] = v1;
    }
  }
  BAR();

  // ---- phase A: Q proj (waves 0,1) / K proj (waves 2,3), both windows ----
  // sbf rows = tokens, cols 0..31 = Q (padded), cols 32..63 = K.
  {
    const bf16_t* wt   = wsb + ((wave < 2) ? WQT_OFF : WKT_OFF);
    const float*  bias = (wave < 2) ? bq : bk;
    const int mbase = (wave & 1) << 5;  // rows 0..31 or 32..63
    const int cofs  = (wave < 2) ? 0 : 32;
    const bool isQ  = (wave < 2);
    f32x4 acc[2][2][2];  // [win][mt][nt]
#pragma unroll
    for (int w2 = 0; w2 < 2; ++w2)
#pragma unroll
      for (int mt = 0; mt < 2; ++mt)
#pragma unroll
        for (int nt = 0; nt < 2; ++nt) acc[w2][mt][nt] = fzero;
#pragma unroll
    for (int k0 = 0; k0 < 256; k0 += 32) {
      bf16x8 b0 = *(const bf16x8*)(wt + l15 * 256 + k0 + g * 8);
      bf16x8 b1 = *(const bf16x8*)(wt + (16 + l15) * 256 + k0 + g * 8);
#pragma unroll
      for (int w2 = 0; w2 < 2; ++w2) {
        const bf16_t* xs = w2 ? xsf1 : xsf0;
        bf16x8 a0 = *(const bf16x8*)&xs[xs_i(mbase + l15, k0 + g * 8)];
        bf16x8 a1 = *(const bf16x8*)&xs[xs_i(mbase + 16 + l15, k0 + g * 8)];
        acc[w2][0][0] = MFMA16(a0, b0, acc[w2][0][0]);
        acc[w2][0][1] = MFMA16(a0, b1, acc[w2][0][1]);
        acc[w2][1][0] = MFMA16(a1, b0, acc[w2][1][0]);
        acc[w2][1][1] = MFMA16(a1, b1, acc[w2][1][1]);
      }
    }
#pragma unroll
    for (int w2 = 0; w2 < 2; ++w2) {
      bf16_t* sb = w2 ? sbf1 : sbf0;
      const int pix = w2 ? pix1 : pix0;
#pragma unroll
      for (int nt = 0; nt < 2; ++nt) {
        const int coln = (nt << 4) + l15;
        const float bval = (coln < kNCLS) ? bias[coln] : 0.f;
#pragma unroll
        for (int mt = 0; mt < 2; ++mt) {
#pragma unroll
          for (int r = 0; r < 4; ++r) {
            const int row = mbase + (mt << 4) + (g << 2) + r;  // token
            const float v = acc[w2][mt][nt][r] + bval;
            sb[sb_i(row, cofs + coln)] = (bf16_t)v;
            if (isQ && coln < kNCLS) {
              out0[(size_t)(pix + ((row >> 3) << 8) + (row & 7)) * kNCLS + coln] = v;
            }
          }
        }
      }
    }
  }
  BAR();

  // ---- phase S: S = Q K^T + in-register softmax -> Ps, both windows ----
  {
    const int mbase = wave << 4;
    f32x4 s[2][4];
#pragma unroll
    for (int w2 = 0; w2 < 2; ++w2) {
      const bf16_t* sb = w2 ? sbf1 : sbf0;
      const bf16x8 aq = *(const bf16x8*)&sb[sb_i(mbase + l15, g * 8)];
#pragma unroll
      for (int nt = 0; nt < 4; ++nt) {
        bf16x8 bk8 = *(const bf16x8*)&sb[sb_i((nt << 4) + l15, 32 + g * 8)];
        s[w2][nt] = MFMA16(aq, bk8, fzero);
      }
    }
    BAR();  // all waves done reading Q/K (Ps aliases them)
#pragma unroll
    for (int w2 = 0; w2 < 2; ++w2) {
      bf16_t* sb = w2 ? sbf1 : sbf0;
#pragma unroll
      for (int r = 0; r < 4; ++r) {
        float m = fmaxf(fmaxf(s[w2][0][r], s[w2][1][r]), fmaxf(s[w2][2][r], s[w2][3][r]));
#pragma unroll
        for (int off = 1; off < 16; off <<= 1) m = fmaxf(m, __shfl_xor(m, off));
        float e0 = __expf(s[w2][0][r] - m), e1 = __expf(s[w2][1][r] - m);
        float e2 = __expf(s[w2][2][r] - m), e3 = __expf(s[w2][3][r] - m);
        float sum = (e0 + e1) + (e2 + e3);
#pragma unroll
        for (int off = 1; off < 16; off <<= 1) sum += __shfl_xor(sum, off);
        const float inv = 1.0f / sum;
        const int row = mbase + (g << 2) + r;
        sb[sb_i(row, l15)]      = (bf16_t)(e0 * inv);
        sb[sb_i(row, 16 + l15)] = (bf16_t)(e1 * inv);
        sb[sb_i(row, 32 + l15)] = (bf16_t)(e2 * inv);
        sb[sb_i(row, 48 + l15)] = (bf16_t)(e3 * inv);
      }
    }
  }
  BAR();  // P visible to all waves

  // ---- hoist P fragments to registers, both windows (64 VGPRs) ----
  bf16x8 bp[2][4][2];
#pragma unroll
  for (int w2 = 0; w2 < 2; ++w2) {
    const bf16_t* sb = w2 ? sbf1 : sbf0;
#pragma unroll
    for (int nt = 0; nt < 4; ++nt) {
      bp[w2][nt][0] = *(const bf16x8*)&sb[sb_i((nt << 4) + l15, g * 8)];
      bp[w2][nt][1] = *(const bf16x8*)&sb[sb_i((nt << 4) + l15, 32 + g * 8)];
    }
  }
  // NOTE: no BAR yet -- Bc0's k-loop below touches no LDS writes; the BAR
  // before the first slice-write protects Ps for all waves' hoists AND
  // lets the hoist latency hide under Bc0's compute.

  // ---- pipelined tail ----
  // Bc k-loop: U chunk for both windows into accV (registers only).
  auto bc_kloop = [&](int chunk, f32x4 (&accV)[2][4]) {
    const bf16_t* wft = wsb + WFT_OFF + (size_t)((chunk << 6) + (wave << 4)) * 256;
#pragma unroll
    for (int w2 = 0; w2 < 2; ++w2)
#pragma unroll
      for (int mt = 0; mt < 4; ++mt) accV[w2][mt] = fzero;
#pragma unroll
    for (int k0 = 0; k0 < 256; k0 += 32) {
      bf16x8 bf = *(const bf16x8*)(wft + l15 * 256 + k0 + g * 8);  // shared A/B
#pragma unroll
      for (int w2 = 0; w2 < 2; ++w2) {
        const bf16_t* xs = w2 ? xsf1 : xsf0;
#pragma unroll
        for (int mt = 0; mt < 4; ++mt) {
          bf16x8 af = *(const bf16x8*)&xs[xs_i((mt << 4) + l15, k0 + g * 8)];
          accV[w2][mt] = MFMA16(af, bf, accV[w2][mt]);
        }
      }
    }
  };

  f32x4 accV[2][4];  // [win][mt]
  bc_kloop(0, accV);
  BAR();  // Ps-protect (hoists done everywhere) + cadence anchor

  for (int chunk = 0; chunk < 4; ++chunk) {
    // slice-write (wave-private rows) + PV + fused-epilogue stores
    const int c2 = (chunk << 6) + (wave << 4) + (g << 2);
    const f32x4 bfv = *(const f32x4*)(bff + c2);
#pragma unroll
    for (int w2 = 0; w2 < 2; ++w2) {
      bf16_t* sb = w2 ? sbf1 : sbf0;
      const bf16_t* xs = w2 ? xsf1 : xsf0;
      const int pix = w2 ? pix1 : pix0;
#pragma unroll
      for (int mt = 0; mt < 4; ++mt) {
        bf16x4 pk;
#pragma unroll
        for (int r = 0; r < 4; ++r) pk[r] = (bf16_t)accV[w2][mt][r];
        *(bf16x4*)&sb[sb_i((wave << 4) + l15, (mt << 4) + (g << 2))] = pk;
      }
      const bf16x8 av0 = *(const bf16x8*)&sb[sb_i((wave << 4) + l15, g * 8)];
      const bf16x8 av1 = *(const bf16x8*)&sb[sb_i((wave << 4) + l15, 32 + g * 8)];
#pragma unroll
      for (int nt = 0; nt < 4; ++nt) {
        f32x4 accC = MFMA16(av0, bp[w2][nt][0], fzero);
        accC = MFMA16(av1, bp[w2][nt][1], accC);
        const int t = (nt << 4) + l15;
        const bf16x4 xv = *(const bf16x4*)&xs[xs_i(t, c2)];
        f32x4 o;
#pragma unroll
        for (int r = 0; r < 4; ++r)
          o[r] = gm * (accC[r] + bfv[r]) + (float)xv[r];
        *(f32x4*)(out1 + (size_t)(pix + ((t >> 3) << 8) + (t & 7)) * kC + c2) = o;
      }
    }
    // overlap next chunk's compute with this chunk's store drain
    if (chunk < 3) {
      bc_kloop(chunk + 1, accV);
      BAR();  // one BAR per chunk between store phases (clean-cadence law)
    }
  }
}

extern "C" void kernel_launch(void* const* d_in, const int* in_sizes, int n_in,
                              void* d_out, int out_size, void* d_ws, size_t ws_size,
                              hipStream_t stream)
{
  const float* x     = (const float*)d_in[0];
  const float* Wq    = (const float*)d_in[1];
  const float* bq    = (const float*)d_in[2];
  const float* Wk    = (const float*)d_in[3];
  const float* bk    = (const float*)d_in[4];
  const float* Wv    = (const float*)d_in[5];
  const float* bv    = (const float*)d_in[6];
  const float* Wres  = (const float*)d_in[7];
  const float* bres  = (const float*)d_in[8];
  const float* gamma = (const float*)d_in[9];
  bf16_t* wsb = (bf16_t*)d_ws;                         // 81920 bf16 = 163840 B
  float*  bff = (float*)((char*)d_ws + BF_BYTE_OFF);   // + 1024 B
  float* out0 = (float*)d_out;                         // (8,256,256,18)
  float* out1 = out0 + (size_t)8 * 256 * 256 * 18;     // (8,256,256,256)

  prep_kernel<<<dim3(321), dim3(256), 0, stream>>>(Wq, Wk, Wv, bv, Wres, bres, wsb, bff);
  semwin_main<<<dim3(4096), dim3(256), 0, stream>>>(x, bq, bk, gamma, wsb, bff, out0, out1);
}